// Round 15
// baseline (372.584 us; speedup 1.0000x reference)
//
#include <hip/hip_runtime.h>
#include <cstdint>
#include <cstddef>

#define NN 100000
#define NE 1600000
#define F  128
#define NPAD 100352          // 98 * 1024
#define NBUCK 782            // ceil(NN / 128) buckets of 128 nodes
#define BCAPG 2560           // padded region capacity per bucket (mean 2046, +11 sd)
#define FILLB 1024           // fill-role blocks
#define CHUNK 1563           // ceil(NE / FILLB)

typedef __attribute__((ext_vector_type(8))) short bf16x8;
typedef __attribute__((ext_vector_type(4))) float f32x4;

// bf16 helpers (RNE)
__device__ __forceinline__ unsigned short f2bf(float f) {
    unsigned u = __float_as_uint(f);
    unsigned r = (u + 0x7fffu + ((u >> 16) & 1u)) >> 16;
    return (unsigned short)r;
}
__device__ __forceinline__ void acc_bf8s(const uint4 v, const float ns, float* acc) {
    acc[0] += __uint_as_float(v.x << 16) * ns;
    acc[1] += __uint_as_float(v.x & 0xffff0000u) * ns;
    acc[2] += __uint_as_float(v.y << 16) * ns;
    acc[3] += __uint_as_float(v.y & 0xffff0000u) * ns;
    acc[4] += __uint_as_float(v.z << 16) * ns;
    acc[5] += __uint_as_float(v.z & 0xffff0000u) * ns;
    acc[6] += __uint_as_float(v.w << 16) * ns;
    acc[7] += __uint_as_float(v.w & 0xffff0000u) * ns;
}
__device__ __forceinline__ float deg2norm(int d) {
    return rsqrtf((float)max(d, 1));
}

// ---------------- kernel 1: cast x->bf16 + edge binning + deg_out + setup ----------------
// g in [0,1152): g%9==4 -> cast role (128 blocks); else fill role (1024 blocks)
// g in [1152,1281): setup role: V[i] = (W2[i].Wp_a, W2[i].Wp_c); i==128 -> consts
__global__ __launch_bounds__(256, 3)
void cast_fill_kernel(const float* __restrict__ x, unsigned short* __restrict__ xb,
                      const int* __restrict__ src, const int* __restrict__ dst,
                      int* __restrict__ deg_out, int* __restrict__ gCur,
                      int* __restrict__ srcPart,
                      const float* __restrict__ W2, const float* __restrict__ Wp,
                      const float* __restrict__ b2, const float* __restrict__ bp,
                      float* __restrict__ consts, float2* __restrict__ V) {
    __shared__ __align__(16) char smem[15664];
    const int g = blockIdx.x;
    const int tid = threadIdx.x;

    if (g >= 1152) {                                // ---- setup role (129 blocks)
        const int i = g - 1152;
        if (i < 128) {
            float* red = (float*)smem;
            float pa = 0.f, pc = 0.f;
            if (tid < 128) {
                const float wv = W2[i * F + tid];
                pa = wv * Wp[tid];
                pc = wv * Wp[F + tid];
            }
            #pragma unroll
            for (int m = 32; m > 0; m >>= 1) {
                pa += __shfl_xor(pa, m);
                pc += __shfl_xor(pc, m);
            }
            if (tid < 128 && (tid & 63) == 0) {
                red[(tid >> 6) * 2]     = pa;
                red[(tid >> 6) * 2 + 1] = pc;
            }
            __syncthreads();
            if (tid == 0) V[i] = make_float2(red[0] + red[2], red[1] + red[3]);
        } else if (tid < 64) {                      // consts
            const float2 bb = *(const float2*)&b2[2 * tid];
            const float2 wa = *(const float2*)&Wp[2 * tid];
            const float2 wc = *(const float2*)&Wp[F + 2 * tid];
            float s = bb.x * (wa.x + wc.x) + bb.y * (wa.y + wc.y);
            #pragma unroll
            for (int m = 32; m > 0; m >>= 1) s += __shfl_xor(s, m);
            if (tid == 0) consts[0] = s + bp[0];
        }
        return;
    }

    const int r9 = g % 9;
    if (r9 == 4) {                                  // ---- cast role (128 blocks)
        const int cb = g / 9;                       // 0..127
        const int total8 = NN * F / 8;              // 1.6M
        for (int i = cb * 256 + tid; i < total8; i += 128 * 256) {
            const float4 v0 = *(const float4*)&x[(size_t)i * 8];
            const float4 v1 = *(const float4*)&x[(size_t)i * 8 + 4];
            short h8[8];
            h8[0] = (short)f2bf(v0.x); h8[1] = (short)f2bf(v0.y);
            h8[2] = (short)f2bf(v0.z); h8[3] = (short)f2bf(v0.w);
            h8[4] = (short)f2bf(v1.x); h8[5] = (short)f2bf(v1.y);
            h8[6] = (short)f2bf(v1.z); h8[7] = (short)f2bf(v1.w);
            *(bf16x8*)&xb[(size_t)i * 8] = *(bf16x8*)h8;
        }
        return;
    }

    // ---- fill role (1024 blocks)
    int* packedL = (int*)smem;                      // CHUNK ints (6252 B)
    unsigned short* bktL = (unsigned short*)(packedL + CHUNK);  // CHUNK u16 (3126 B)
    int* hist = (int*)(smem + 9380);                // NBUCK ints
    int* curL = hist + NBUCK;                       // NBUCK ints
    const int fid = (g / 9) * 8 + (r9 > 4 ? r9 - 1 : r9);   // 0..1023
    const int e0 = fid * CHUNK;
    const int nCh = min(CHUNK, NE - e0);
    for (int i = tid; i < NBUCK; i += 256) hist[i] = 0;
    __syncthreads();
    for (int i = tid; i < nCh; i += 256) {
        const int s = src[e0 + i];
        const int d = dst[e0 + i];
        atomicAdd(&deg_out[s], 1);
        const int bkt = d >> 7;
        atomicAdd(&hist[bkt], 1);
        packedL[i] = s | ((d & 127) << 17);
        bktL[i] = (unsigned short)bkt;
    }
    __syncthreads();
    for (int b = tid; b < NBUCK; b += 256) {
        const int c = hist[b];
        curL[b] = (c > 0) ? (b * BCAPG + atomicAdd(&gCur[b], c)) : 0;
    }
    __syncthreads();
    for (int i = tid; i < nCh; i += 256) {
        const int bkt = bktL[i];
        const int p = atomicAdd(&curL[bkt], 1);
        if (p < (bkt + 1) * BCAPG)
            srcPart[p] = packedL[i];
    }
}

// ---------------- kernel 2: sort + gather(x) + per-bucket mini-GEMM @W1 + head fold ----------------
// Per 128-node bucket: count/scan/sort (as before); gather g[n][:] = sum_e ns[src]*xb[src][:]
// into LDS (bf16, MFMA A-frag layout); then block mini-GEMM g@W1 with relu/bias/V epilogue:
// uw[n] = ns[n] * ( relu(g[n]@W1 * nd[n] + b1) . V_{a,c} )
__global__ __launch_bounds__(256)
void gather_gemm_kernel(const unsigned short* __restrict__ xb,
                        int* __restrict__ srcPart, const int* __restrict__ gCur,
                        const int* __restrict__ deg_out, const float* __restrict__ W1,
                        const float* __restrict__ b1, const float2* __restrict__ V,
                        float2* __restrict__ uw, int* __restrict__ offs,
                        int* __restrict__ ends, float* __restrict__ norm_dst) {
    __shared__ int cnt[128];
    __shared__ int loc[128];
    __shared__ int cur[128];
    __shared__ int sortedL[BCAPG];                  // 10240 B
    __shared__ __align__(16) char gS[32768];        // 128x128 bf16, A-frag layout

    const int b   = blockIdx.x;
    const int tid = threadIdx.x;
    const int nlo = b * 128;
    const int nCnt = min(128, NN - nlo);
    const int eBase = b * BCAPG;
    const int total = min(gCur[b], BCAPG);

    if (tid < 128) cnt[tid] = 0;
    __syncthreads();
    for (int i = tid; i < total; i += 256)
        atomicAdd(&cnt[(srcPart[eBase + i] >> 17) & 127], 1);
    __syncthreads();
    if (tid < 128) loc[tid] = cnt[tid];
    __syncthreads();
    for (int off = 1; off < 128; off <<= 1) {
        int v = 0;
        if (tid < 128 && tid >= off) v = loc[tid - off];
        __syncthreads();
        if (tid < 128) loc[tid] += v;
        __syncthreads();
    }
    if (tid < 128) cur[tid] = loc[tid] - cnt[tid];
    if (tid < nCnt) {
        const int st = eBase + loc[tid] - cnt[tid];
        offs[nlo + tid] = st;
        ends[nlo + tid] = st + cnt[tid];
        norm_dst[nlo + tid] = deg2norm(cnt[tid]);
    }
    __syncthreads();
    for (int i = tid; i < total; i += 256) {
        const int v = srcPart[eBase + i];
        const int r = atomicAdd(&cur[(v >> 17) & 127], 1);
        sortedL[r] = v & 0x1FFFF;
    }
    __syncthreads();
    // coalesced write of sorted src ids (for ac_kernel)
    for (int i = tid; i < total; i += 256)
        srcPart[eBase + i] = sortedL[i];

    // ---- gather g rows (per wave: 32 nodes; 16 lanes per edge, 8 bf16 cols/lane)
    const int w    = tid >> 6;
    const int lane = tid & 63;
    const int q    = lane >> 4;
    const int ml   = lane & 15;
    const int c8   = ml * 8;

    const int nhEnd = min((w + 1) * 32, nCnt);
    for (int nh = w * 32; nh < nhEnd; ++nh) {
        const int end = loc[nh];
        const int beg = end - cnt[nh];
        float acc[8] = {0.f, 0.f, 0.f, 0.f, 0.f, 0.f, 0.f, 0.f};
        int j = beg;
        for (; j + 16 <= end; j += 16) {      // 16 edges in flight per wave
            const int s0 = sortedL[j + q];
            const int s1 = sortedL[j + 4 + q];
            const int s2 = sortedL[j + 8 + q];
            const int s3 = sortedL[j + 12 + q];
            const float ns0 = deg2norm(deg_out[s0]);
            const float ns1 = deg2norm(deg_out[s1]);
            const float ns2 = deg2norm(deg_out[s2]);
            const float ns3 = deg2norm(deg_out[s3]);
            const uint4 v0 = *(const uint4*)&xb[(size_t)s0 * F + c8];
            const uint4 v1 = *(const uint4*)&xb[(size_t)s1 * F + c8];
            const uint4 v2 = *(const uint4*)&xb[(size_t)s2 * F + c8];
            const uint4 v3 = *(const uint4*)&xb[(size_t)s3 * F + c8];
            acc_bf8s(v0, ns0, acc);
            acc_bf8s(v1, ns1, acc);
            acc_bf8s(v2, ns2, acc);
            acc_bf8s(v3, ns3, acc);
        }
        for (; j + 8 <= end; j += 8) {
            const int s0 = sortedL[j + q];
            const int s1 = sortedL[j + 4 + q];
            const float ns0 = deg2norm(deg_out[s0]);
            const float ns1 = deg2norm(deg_out[s1]);
            const uint4 v0 = *(const uint4*)&xb[(size_t)s0 * F + c8];
            const uint4 v1 = *(const uint4*)&xb[(size_t)s1 * F + c8];
            acc_bf8s(v0, ns0, acc);
            acc_bf8s(v1, ns1, acc);
        }
        for (; j + 4 <= end; j += 4) {
            const int s = sortedL[j + q];
            const float ns = deg2norm(deg_out[s]);
            const uint4 v = *(const uint4*)&xb[(size_t)s * F + c8];
            acc_bf8s(v, ns, acc);
        }
        if (j + q < end) {
            const int s = sortedL[j + q];
            const float ns = deg2norm(deg_out[s]);
            const uint4 v = *(const uint4*)&xb[(size_t)s * F + c8];
            acc_bf8s(v, ns, acc);
        }
        #pragma unroll
        for (int k = 0; k < 8; ++k) {
            acc[k] += __shfl_xor(acc[k], 16);
            acc[k] += __shfl_xor(acc[k], 32);
        }
        // write g row nh, k-octet ml (MFMA A-frag layout) from q==0 lanes
        if (q == 0) {
            short h8[8];
            #pragma unroll
            for (int k = 0; k < 8; ++k) h8[k] = (short)f2bf(acc[k]);
            const int kb2 = ml >> 2, q2 = ml & 3, ml2 = nh & 15, mh2 = nh >> 4;
            *(bf16x8*)(gS + (((mh2 * 4 + kb2) * 64) + q2 * 16 + ml2) * 16) = *(bf16x8*)h8;
        }
    }
    __syncthreads();

    // ---- mini-GEMM: g(128x128) @ W1(128x128); wave w -> rows 32w..32w+31
    f32x4 oa[2][8];
    #pragma unroll
    for (int mh = 0; mh < 2; ++mh)
        #pragma unroll
        for (int nb = 0; nb < 8; ++nb) oa[mh][nb] = (f32x4){0.f, 0.f, 0.f, 0.f};

    #pragma unroll
    for (int kb = 0; kb < 4; ++kb) {
        const bf16x8 a0 = *(const bf16x8*)(gS + ((((2 * w + 0) * 4 + kb) * 64) + lane) * 16);
        const bf16x8 a1 = *(const bf16x8*)(gS + ((((2 * w + 1) * 4 + kb) * 64) + lane) * 16);
        const int k0 = kb * 32 + q * 8;
        #pragma unroll
        for (int nb = 0; nb < 8; ++nb) {
            const int ncol = nb * 16 + ml;
            short bf8a[8];
            #pragma unroll
            for (int j = 0; j < 8; ++j)
                bf8a[j] = (short)f2bf(W1[(k0 + j) * F + ncol]);
            const bf16x8 bf = *(bf16x8*)bf8a;
            oa[0][nb] = __builtin_amdgcn_mfma_f32_16x16x32_bf16(a0, bf, oa[0][nb], 0, 0, 0);
            oa[1][nb] = __builtin_amdgcn_mfma_f32_16x16x32_bf16(a1, bf, oa[1][nb], 0, 0, 0);
        }
    }

    // epilogue: relu(out*nd + b1) . V, reduce over cols, write uw
    float b1v[8]; float2 Vv[8];
    #pragma unroll
    for (int nb = 0; nb < 8; ++nb) {
        b1v[nb] = b1[nb * 16 + ml];
        Vv[nb]  = V[nb * 16 + ml];
    }
    #pragma unroll
    for (int mh = 0; mh < 2; ++mh) {
        #pragma unroll
        for (int r = 0; r < 4; ++r) {
            const int row = 32 * w + mh * 16 + q * 4 + r;   // bucket row 0..127
            const float nd = deg2norm(cnt[row]);
            float pa = 0.f, pc = 0.f;
            #pragma unroll
            for (int nb = 0; nb < 8; ++nb) {
                const float ok = fmaxf(oa[mh][nb][r] * nd + b1v[nb], 0.f);
                pa += ok * Vv[nb].x;
                pc += ok * Vv[nb].y;
            }
            #pragma unroll
            for (int m = 1; m <= 8; m <<= 1) {
                pa += __shfl_xor(pa, m);
                pc += __shfl_xor(pc, m);
            }
            if (ml == 0 && row < nCnt) {
                const int n = nlo + row;
                const float ns = deg2norm(deg_out[n]);
                uw[n] = make_float2(ns * pa, ns * pc);
            }
        }
    }
}

// ---------------- layer-2 scalar aggregation (8 lanes per node) ----------------
__global__ void ac_kernel(const float2* __restrict__ uw, const int* __restrict__ sorted_src,
                          const int* __restrict__ offs, const int* __restrict__ ends,
                          const float* __restrict__ norm_dst,
                          float* __restrict__ A, float* __restrict__ C, int nN) {
    const int gid = blockIdx.x * blockDim.x + threadIdx.x;
    const int n   = gid >> 3;
    if (n >= nN) return;
    const int sub = gid & 7;
    const int beg = offs[n];
    const int end = ends[n];
    float su = 0.f, sw = 0.f;
    for (int j = beg + sub; j < end; j += 8) {
        const float2 t = uw[sorted_src[j]];
        su += t.x;
        sw += t.y;
    }
    su += __shfl_xor(su, 1); sw += __shfl_xor(sw, 1);
    su += __shfl_xor(su, 2); sw += __shfl_xor(sw, 2);
    su += __shfl_xor(su, 4); sw += __shfl_xor(sw, 4);
    if (sub == 0) {
        const float nd = norm_dst[n];
        A[n] = nd * su;
        C[n] = nd * sw;
    }
}

// ---------------- edge scores (4-wide) ----------------
__global__ void score_kernel(const float* __restrict__ A, const float* __restrict__ C,
                             const int4* __restrict__ src4, const int4* __restrict__ dst4,
                             const float* __restrict__ consts, float4* __restrict__ out4,
                             int nE4) {
    const int i = blockIdx.x * blockDim.x + threadIdx.x;
    if (i < nE4) {
        const int4 s = src4[i];
        const int4 d = dst4[i];
        const float cc = consts[0];
        float4 o;
        o.x = 1.f / (1.f + __expf(-(A[s.x] + C[d.x] + cc)));
        o.y = 1.f / (1.f + __expf(-(A[s.y] + C[d.y] + cc)));
        o.z = 1.f / (1.f + __expf(-(A[s.z] + C[d.z] + cc)));
        o.w = 1.f / (1.f + __expf(-(A[s.w] + C[d.w] + cc)));
        out4[i] = o;
    }
}

extern "C" void kernel_launch(void* const* d_in, const int* in_sizes, int n_in,
                              void* d_out, int out_size, void* d_ws, size_t ws_size,
                              hipStream_t stream) {
    const float* x  = (const float*)d_in[0];
    const float* W1 = (const float*)d_in[1];
    const float* b1 = (const float*)d_in[2];
    const float* W2 = (const float*)d_in[3];
    const float* b2 = (const float*)d_in[4];
    const float* Wp = (const float*)d_in[5];
    const float* bp = (const float*)d_in[6];
    const int*   src = (const int*)d_in[7];
    const int*   dst = (const int*)d_in[8];
    float* out = (float*)d_out;

    float* ws        = (float*)d_ws;
    float* bufA      = ws;                        // NPAD: deg_out(int), later A[]
    int*   gCur      = (int*)(ws + NPAD);         // 1024 (0-based counts)
    float* bufC      = ws + NPAD + 1024;          // NPAD: C[]
    float* norm_dst  = bufC + NPAD;               // NPAD
    int*   offs      = (int*)(norm_dst + NPAD);   // NPAD
    int*   ends      = offs + NPAD;               // NPAD
    float* consts    = (float*)(ends + NPAD);     // 16
    float2* V        = (float2*)(consts + 16);    // 128 float2
    float2* uw       = V + 128;                   // NN float2
    int*   srcPart   = (int*)(uw + NN);           // NBUCK*BCAPG ints (8.0 MB)
    unsigned short* xb = (unsigned short*)(srcPart + (size_t)NBUCK * BCAPG);  // NN*F bf16

    // zero deg_out + gCur in one memset
    hipMemsetAsync(bufA, 0, (NPAD + 1024) * sizeof(int), stream);

    // cast x->bf16 + edge binning + deg_out + setup (V, consts) in one kernel
    cast_fill_kernel<<<1281, 256, 0, stream>>>(x, xb, src, dst, (int*)bufA, gCur, srcPart,
                                               W2, Wp, b2, bp, consts, V);

    // per-bucket sort + gather(x) + mini-GEMM @W1 + head fold -> uw, offs/ends, norm_dst
    gather_gemm_kernel<<<NBUCK, 256, 0, stream>>>(xb, srcPart, gCur, (const int*)bufA,
                                                  W1, b1, V, uw, offs, ends, norm_dst);

    // layer-2 aggregation collapsed to scalar sums (8 lanes/node)
    ac_kernel<<<(NN * 8 + 255) / 256, 256, 0, stream>>>(uw, srcPart, offs, ends, norm_dst,
                                                        bufA, bufC, NN);

    // edge scores (NE divisible by 4)
    score_kernel<<<(NE / 4 + 255) / 256, 256, 0, stream>>>(bufA, bufC, (const int4*)src,
                                                           (const int4*)dst, consts,
                                                           (float4*)out, NE / 4);
}

// Round 16
// 313.392 us; speedup vs baseline: 1.1889x; 1.1889x over previous
//
#include <hip/hip_runtime.h>
#include <cstdint>
#include <cstddef>

#define NN 100000
#define NE 1600000
#define F  128
#define NPAD 100352          // 98 * 1024
#define NBUCK 782            // ceil(NN / 128) buckets of 128 nodes
#define BCAPG 2560           // padded region capacity per bucket (mean 2046, +11 sd)
#define CHUNK 4167           // ceil(NE / 384) fill blocks

typedef __attribute__((ext_vector_type(8))) short bf16x8;
typedef __attribute__((ext_vector_type(4))) float f32x4;

// bf16 helpers (RNE)
__device__ __forceinline__ unsigned short f2bf(float f) {
    unsigned u = __float_as_uint(f);
    unsigned r = (u + 0x7fffu + ((u >> 16) & 1u)) >> 16;
    return (unsigned short)r;
}
__device__ __forceinline__ void acc_bf8s(const uint4 v, const float ns, float* acc) {
    acc[0] += __uint_as_float(v.x << 16) * ns;
    acc[1] += __uint_as_float(v.x & 0xffff0000u) * ns;
    acc[2] += __uint_as_float(v.y << 16) * ns;
    acc[3] += __uint_as_float(v.y & 0xffff0000u) * ns;
    acc[4] += __uint_as_float(v.z << 16) * ns;
    acc[5] += __uint_as_float(v.z & 0xffff0000u) * ns;
    acc[6] += __uint_as_float(v.w << 16) * ns;
    acc[7] += __uint_as_float(v.w & 0xffff0000u) * ns;
}

// ---------------- setup: bucket cursors + head constant + V = W2 @ Wp ----------------
__global__ void setup_kernel(int* __restrict__ gCur,
                             const float* __restrict__ W2, const float* __restrict__ Wp,
                             const float* __restrict__ b2, const float* __restrict__ bp,
                             float* __restrict__ consts, float2* __restrict__ V) {
    const int g = blockIdx.x;
    const int tid = threadIdx.x;
    if (g < 4) {
        const int b = g * 256 + tid;
        if (b < NBUCK) gCur[b] = b * BCAPG;
        return;
    }
    // block 4: head fold weights + constant
    if (tid < 128) {                      // V[i] = (W2[i]·Wp_a, W2[i]·Wp_c)
        float sa = 0.f, sc = 0.f;
        #pragma unroll 8
        for (int j = 0; j < F; ++j) {
            const float w = W2[tid * F + j];
            sa += w * Wp[j];
            sc += w * Wp[F + j];
        }
        V[tid] = make_float2(sa, sc);
    } else if (tid < 192) {               // wave 2: cc = b2.Wp_a + b2.Wp_c + bp
        const int l = tid - 128;
        const float2 bb = *(const float2*)&b2[2 * l];
        const float2 wa = *(const float2*)&Wp[2 * l];
        const float2 wc = *(const float2*)&Wp[F + 2 * l];
        float s = bb.x * (wa.x + wc.x) + bb.y * (wa.y + wc.y);
        #pragma unroll
        for (int m = 32; m > 0; m >>= 1) s += __shfl_xor(s, m);
        if (l == 0) consts[0] = s + bp[0];
    }
}

// ---------------- fused gemm1 (MFMA, B-in-registers) + binning ----------------
// blockIdx%2==1 -> fill role: LDS-staged bucket binning + deg_out atomics
// blockIdx%2==0 -> gemm role: hs_bf[n][:] = bf16(x[n][:] @ W1), single bf16 MFMA
__global__ __launch_bounds__(256, 3)
void gemm1_fill_kernel(const float* __restrict__ in, const float* __restrict__ W,
                       unsigned short* __restrict__ out_bf,
                       const int* __restrict__ src, const int* __restrict__ dst,
                       int* __restrict__ deg_out, int* __restrict__ gCur,
                       int* __restrict__ srcPart) {
    __shared__ __align__(16) char smem[31264];

    const int g = blockIdx.x;
    const int tid = threadIdx.x;

    if (g & 1) {                                    // ---- fill role (384 blocks)
        int* packedL = (int*)smem;                  // CHUNK ints
        unsigned short* bktL = (unsigned short*)(packedL + CHUNK);  // CHUNK u16
        int* hist = (int*)((char*)smem + 25008);    // NBUCK ints
        int* curL = hist + NBUCK;                   // NBUCK ints
        const int e0 = (g >> 1) * CHUNK;
        const int nCh = min(CHUNK, NE - e0);
        for (int i = tid; i < NBUCK; i += 256) hist[i] = 0;
        __syncthreads();
        for (int i = tid; i < nCh; i += 256) {
            const int s = src[e0 + i];
            const int d = dst[e0 + i];
            atomicAdd(&deg_out[s], 1);
            const int bkt = d >> 7;
            atomicAdd(&hist[bkt], 1);
            packedL[i] = s | ((d & 127) << 17);
            bktL[i] = (unsigned short)bkt;
        }
        __syncthreads();
        for (int b = tid; b < NBUCK; b += 256) {
            const int c = hist[b];
            curL[b] = (c > 0) ? atomicAdd(&gCur[b], c) : 0;
        }
        __syncthreads();
        for (int i = tid; i < nCh; i += 256) {
            const int bkt = bktL[i];
            const int p = atomicAdd(&curL[bkt], 1);
            if (p < (bkt + 1) * BCAPG)
                srcPart[p] = packedL[i];
        }
        return;
    }

    // ---- gemm role (384 blocks), tile = 32 rows x 128 cols
    char* A_s = smem;                   // 8 KB fragment-ordered A tile (bf16)

    const int gid  = g >> 1;
    const int w    = tid >> 6;          // wave 0..3 -> cols 32w..32w+31
    const int lane = tid & 63;
    const int ml   = lane & 15;
    const int quad = lane >> 4;

    // preload B frags once: Bf[kb][nb], j: bf16(W[(kb*32+quad*8+j)*F + 32w+nb*16+ml])
    bf16x8 Bf[4][2];
    #pragma unroll
    for (int kb = 0; kb < 4; ++kb) {
        #pragma unroll
        for (int nb = 0; nb < 2; ++nb) {
            const int n = 32 * w + nb * 16 + ml;
            const int k0 = kb * 32 + quad * 8;
            #pragma unroll
            for (int j = 0; j < 8; ++j)
                Bf[kb][nb][j] = (short)f2bf(W[(k0 + j) * F + n]);
        }
    }

    const int nTiles = NN / 32;                     // 3125
    for (int tile = gid; tile < nTiles; tile += 384) {
        const int row0 = tile * 32;
        __syncthreads();
        // stage A tile in fragment order: 512 chunks of 8 floats -> bf16
        #pragma unroll
        for (int c = 0; c < 2; ++c) {
            const int i2 = tid + 256 * c;           // 0..511
            const int m  = i2 >> 4;                 // row 0..31
            const int o  = i2 & 15;                 // k-octet
            const float* xr = &in[(size_t)(row0 + m) * F + o * 8];
            const float4 v0 = *(const float4*)xr;
            const float4 v1 = *(const float4*)(xr + 4);
            short h8[8];
            h8[0] = (short)f2bf(v0.x); h8[1] = (short)f2bf(v0.y);
            h8[2] = (short)f2bf(v0.z); h8[3] = (short)f2bf(v0.w);
            h8[4] = (short)f2bf(v1.x); h8[5] = (short)f2bf(v1.y);
            h8[6] = (short)f2bf(v1.z); h8[7] = (short)f2bf(v1.w);
            const int kb2 = o >> 2, q2 = o & 3, ml2 = m & 15, mh2 = m >> 4;
            const int fo = (((mh2 * 4 + kb2) * 64) + q2 * 16 + ml2) * 16;
            *(bf16x8*)(A_s + fo) = *(bf16x8*)h8;
        }
        __syncthreads();

        f32x4 acc00 = {0,0,0,0}, acc01 = {0,0,0,0}, acc10 = {0,0,0,0}, acc11 = {0,0,0,0};
        #pragma unroll
        for (int kb = 0; kb < 4; ++kb) {
            const bf16x8 ah0 = *(const bf16x8*)(A_s + (kb * 64 + lane) * 16);
            const bf16x8 ah1 = *(const bf16x8*)(A_s + ((4 + kb) * 64 + lane) * 16);
            acc00 = __builtin_amdgcn_mfma_f32_16x16x32_bf16(ah0, Bf[kb][0], acc00, 0, 0, 0);
            acc01 = __builtin_amdgcn_mfma_f32_16x16x32_bf16(ah0, Bf[kb][1], acc01, 0, 0, 0);
            acc10 = __builtin_amdgcn_mfma_f32_16x16x32_bf16(ah1, Bf[kb][0], acc10, 0, 0, 0);
            acc11 = __builtin_amdgcn_mfma_f32_16x16x32_bf16(ah1, Bf[kb][1], acc11, 0, 0, 0);
        }

        // epilogue: C/D layout col=lane&15, row=quad*4+reg
        #pragma unroll
        for (int mh = 0; mh < 2; ++mh) {
            #pragma unroll
            for (int nb = 0; nb < 2; ++nb) {
                const f32x4 a = (mh == 0) ? (nb == 0 ? acc00 : acc01)
                                          : (nb == 0 ? acc10 : acc11);
                const int row = row0 + mh * 16 + quad * 4;
                const int col = 32 * w + nb * 16 + ml;
                #pragma unroll
                for (int r = 0; r < 4; ++r)
                    out_bf[(size_t)(row + r) * F + col] = f2bf(a[r]);
            }
        }
    }
}

__global__ void normsrc_kernel(const int* __restrict__ deg_out, float* __restrict__ norm_src, int nN) {
    const int n = blockIdx.x * blockDim.x + threadIdx.x;
    if (n < nN) norm_src[n] = rsqrtf((float)max(deg_out[n], 1));
}

// ---------------- gather + per-bucket LDS counting sort + fused layer-2 head fold ----------------
__global__ __launch_bounds__(256)
void gather_sort_kernel(const unsigned short* __restrict__ hs,
                        int* __restrict__ srcPart, const int* __restrict__ gCur,
                        const float* __restrict__ norm_src, const float* __restrict__ bias,
                        const float2* __restrict__ V, float2* __restrict__ uw,
                        int* __restrict__ offs, int* __restrict__ ends,
                        float* __restrict__ norm_dst) {
    __shared__ int cnt[128];
    __shared__ int loc[128];       // inclusive prefix
    __shared__ int cur[128];
    __shared__ int sortedL[BCAPG];

    const int b   = blockIdx.x;
    const int tid = threadIdx.x;
    const int nlo = b * 128;
    const int nCnt = min(128, NN - nlo);
    const int eBase = b * BCAPG;
    const int total = min(gCur[b] - eBase, BCAPG);

    if (tid < 128) cnt[tid] = 0;
    __syncthreads();
    for (int i = tid; i < total; i += 256)
        atomicAdd(&cnt[(srcPart[eBase + i] >> 17) & 127], 1);
    __syncthreads();
    if (tid < 128) loc[tid] = cnt[tid];
    __syncthreads();
    for (int off = 1; off < 128; off <<= 1) {
        int v = 0;
        if (tid < 128 && tid >= off) v = loc[tid - off];
        __syncthreads();
        if (tid < 128) loc[tid] += v;
        __syncthreads();
    }
    if (tid < 128) cur[tid] = loc[tid] - cnt[tid];
    if (tid < nCnt) {
        const int st = eBase + loc[tid] - cnt[tid];
        offs[nlo + tid] = st;
        ends[nlo + tid] = st + cnt[tid];
        norm_dst[nlo + tid] = rsqrtf((float)max(cnt[tid], 1));
    }
    __syncthreads();
    for (int i = tid; i < total; i += 256) {
        const int v = srcPart[eBase + i];
        const int r = atomicAdd(&cur[(v >> 17) & 127], 1);
        sortedL[r] = v & 0x1FFFF;
    }
    __syncthreads();
    // coalesced write of sorted src ids (for ac_kernel)
    for (int i = tid; i < total; i += 256)
        srcPart[eBase + i] = sortedL[i];

    // ---- feature gather (per wave: 32 nodes; 16 lanes per edge, 8 bf16 cols/lane)
    const int w  = tid >> 6;
    const int l  = tid & 63;
    const int q  = l >> 4;
    const int c8 = (l & 15) * 8;
    float bb[8];
    *(float4*)&bb[0] = *(const float4*)&bias[c8];
    *(float4*)&bb[4] = *(const float4*)&bias[c8 + 4];
    float2 Vl[8];
    #pragma unroll
    for (int k = 0; k < 8; ++k) Vl[k] = V[c8 + k];

    const int nhEnd = min((w + 1) * 32, nCnt);
    for (int nh = w * 32; nh < nhEnd; ++nh) {
        const int end = loc[nh];
        const int beg = end - cnt[nh];
        float acc[8] = {0.f, 0.f, 0.f, 0.f, 0.f, 0.f, 0.f, 0.f};
        int j = beg;
        for (; j + 16 <= end; j += 16) {      // 16 edges in flight per wave
            const int s0 = sortedL[j + q];
            const int s1 = sortedL[j + 4 + q];
            const int s2 = sortedL[j + 8 + q];
            const int s3 = sortedL[j + 12 + q];
            const float ns0 = norm_src[s0];
            const float ns1 = norm_src[s1];
            const float ns2 = norm_src[s2];
            const float ns3 = norm_src[s3];
            const uint4 v0 = *(const uint4*)&hs[(size_t)s0 * F + c8];
            const uint4 v1 = *(const uint4*)&hs[(size_t)s1 * F + c8];
            const uint4 v2 = *(const uint4*)&hs[(size_t)s2 * F + c8];
            const uint4 v3 = *(const uint4*)&hs[(size_t)s3 * F + c8];
            acc_bf8s(v0, ns0, acc);
            acc_bf8s(v1, ns1, acc);
            acc_bf8s(v2, ns2, acc);
            acc_bf8s(v3, ns3, acc);
        }
        for (; j + 8 <= end; j += 8) {
            const int s0 = sortedL[j + q];
            const int s1 = sortedL[j + 4 + q];
            const float ns0 = norm_src[s0];
            const float ns1 = norm_src[s1];
            const uint4 v0 = *(const uint4*)&hs[(size_t)s0 * F + c8];
            const uint4 v1 = *(const uint4*)&hs[(size_t)s1 * F + c8];
            acc_bf8s(v0, ns0, acc);
            acc_bf8s(v1, ns1, acc);
        }
        for (; j + 4 <= end; j += 4) {
            const int s = sortedL[j + q];
            const float ns = norm_src[s];
            const uint4 v = *(const uint4*)&hs[(size_t)s * F + c8];
            acc_bf8s(v, ns, acc);
        }
        if (j + q < end) {
            const int s = sortedL[j + q];
            const float ns = norm_src[s];
            const uint4 v = *(const uint4*)&hs[(size_t)s * F + c8];
            acc_bf8s(v, ns, acc);
        }
        #pragma unroll
        for (int k = 0; k < 8; ++k) {
            acc[k] += __shfl_xor(acc[k], 16);
            acc[k] += __shfl_xor(acc[k], 32);
        }

        const int n = nlo + nh;
        const float nd = rsqrtf((float)max(cnt[nh], 1));
        float pa = 0.f, pc = 0.f;
        #pragma unroll
        for (int k = 0; k < 8; ++k) {
            const float ok = fmaxf(acc[k] * nd + bb[k], 0.f);
            pa += ok * Vl[k].x;
            pc += ok * Vl[k].y;
        }
        #pragma unroll
        for (int m = 1; m <= 8; m <<= 1) {
            pa += __shfl_xor(pa, m);
            pc += __shfl_xor(pc, m);
        }
        if (l == 0) {
            const float ns = norm_src[n];
            uw[n] = make_float2(ns * pa, ns * pc);
        }
    }
}

// ---------------- layer-2 scalar aggregation ----------------
__global__ void ac_kernel(const float2* __restrict__ uw, const int* __restrict__ sorted_src,
                          const int* __restrict__ offs, const int* __restrict__ ends,
                          const float* __restrict__ norm_dst,
                          float* __restrict__ A, float* __restrict__ C, int nN) {
    const int n = blockIdx.x * blockDim.x + threadIdx.x;
    if (n >= nN) return;
    const int beg = offs[n];
    const int end = ends[n];
    float su = 0.f, sw = 0.f;
    int j = beg;
    for (; j + 2 <= end; j += 2) {
        const float2 t0 = uw[sorted_src[j]];
        const float2 t1 = uw[sorted_src[j + 1]];
        su += t0.x + t1.x;
        sw += t0.y + t1.y;
    }
    if (j < end) {
        const float2 t = uw[sorted_src[j]];
        su += t.x;
        sw += t.y;
    }
    const float nd = norm_dst[n];
    A[n] = nd * su;
    C[n] = nd * sw;
}

// ---------------- edge scores (4-wide) ----------------
__global__ void score_kernel(const float* __restrict__ A, const float* __restrict__ C,
                             const int4* __restrict__ src4, const int4* __restrict__ dst4,
                             const float* __restrict__ consts, float4* __restrict__ out4,
                             int nE4) {
    const int i = blockIdx.x * blockDim.x + threadIdx.x;
    if (i < nE4) {
        const int4 s = src4[i];
        const int4 d = dst4[i];
        const float cc = consts[0];
        float4 o;
        o.x = 1.f / (1.f + __expf(-(A[s.x] + C[d.x] + cc)));
        o.y = 1.f / (1.f + __expf(-(A[s.y] + C[d.y] + cc)));
        o.z = 1.f / (1.f + __expf(-(A[s.z] + C[d.z] + cc)));
        o.w = 1.f / (1.f + __expf(-(A[s.w] + C[d.w] + cc)));
        out4[i] = o;
    }
}

extern "C" void kernel_launch(void* const* d_in, const int* in_sizes, int n_in,
                              void* d_out, int out_size, void* d_ws, size_t ws_size,
                              hipStream_t stream) {
    const float* x  = (const float*)d_in[0];
    const float* W1 = (const float*)d_in[1];
    const float* b1 = (const float*)d_in[2];
    const float* W2 = (const float*)d_in[3];
    const float* b2 = (const float*)d_in[4];
    const float* Wp = (const float*)d_in[5];
    const float* bp = (const float*)d_in[6];
    const int*   src = (const int*)d_in[7];
    const int*   dst = (const int*)d_in[8];
    float* out = (float*)d_out;

    float* ws        = (float*)d_ws;
    float* norm_src  = ws;                        // NPAD
    float* bufA      = ws + NPAD;                 // NPAD: deg_out(int), later A[]
    float* bufC      = ws + 2 * NPAD;             // NPAD: C[]
    float* norm_dst  = ws + 3 * NPAD;             // NPAD
    int*   offs      = (int*)(ws + 4 * NPAD);     // NPAD
    int*   ends      = offs + NPAD;               // NPAD
    int*   gCur      = ends + NPAD;               // 1024
    float* consts    = (float*)(gCur + 1024);     // 16
    float2* V        = (float2*)(consts + 16);    // 128 float2
    float2* uw       = V + 128;                   // NN float2
    int*   srcPart   = (int*)(uw + NN);           // NBUCK*BCAPG ints (8.0 MB)
    unsigned short* hs_bf = (unsigned short*)(srcPart + (size_t)NBUCK * BCAPG);  // NN*F bf16

    // init counters + folded head weights (one setup kernel)
    hipMemsetAsync(bufA, 0, NPAD * sizeof(int), stream);        // deg_out
    setup_kernel<<<5, 256, 0, stream>>>(gCur, W2, Wp, b2, bp, consts, V);

    // layer-1 MFMA GEMM (unnormalized) overlapped with degree count + edge binning
    gemm1_fill_kernel<<<768, 256, 0, stream>>>(x, W1, hs_bf, src, dst,
                                               (int*)bufA, gCur, srcPart);

    normsrc_kernel<<<(NN + 255) / 256, 256, 0, stream>>>((const int*)bufA, norm_src, NN);

    // per-bucket LDS sort + feature gather + folded layer-2 head -> uw, offs/ends, norm_dst
    gather_sort_kernel<<<NBUCK, 256, 0, stream>>>(hs_bf, srcPart, gCur, norm_src, b1,
                                                  V, uw, offs, ends, norm_dst);

    // layer-2 aggregation collapsed to scalar sums
    ac_kernel<<<(NN + 255) / 256, 256, 0, stream>>>(uw, srcPart, offs, ends, norm_dst,
                                                    bufA, bufC, NN);

    // edge scores (NE divisible by 4)
    score_kernel<<<(NE / 4 + 255) / 256, 256, 0, stream>>>(bufA, bufC, (const int4*)src,
                                                           (const int4*)dst, consts,
                                                           (float4*)out, NE / 4);
}